// Round 7
// baseline (450.236 us; speedup 1.0000x reference)
//
#include <hip/hip_runtime.h>
#include <stdint.h>
#include <math.h>

#define FDIM 128
#define KDIM 384
#define NROWS 26112   // 512 hop0 rows + 25600 hop1 rows

struct Cols { int o25[25]; int i25[25]; int o10[10]; int i10[10]; };
struct ColsBoth { Cols c[2]; };

// ---------------- host-side JAX threefry (partitionable=True) ----------------
static inline uint32_t rotl32(uint32_t x, uint32_t r){ return (x<<r)|(x>>(32u-r)); }

static void tf2x32(uint32_t k0, uint32_t k1, uint32_t c0, uint32_t c1,
                   uint32_t& o0, uint32_t& o1){
  const uint32_t ra[4] = {13u,15u,26u,6u};
  const uint32_t rb[4] = {17u,29u,16u,24u};
  uint32_t ks2 = k0 ^ k1 ^ 0x1BD11BDAu;
  uint32_t x0 = c0 + k0, x1 = c1 + k1;
  for(int i=0;i<4;i++){ x0 += x1; x1 = rotl32(x1, ra[i]); x1 ^= x0; }
  x0 += k1; x1 += ks2 + 1u;
  for(int i=0;i<4;i++){ x0 += x1; x1 = rotl32(x1, rb[i]); x1 ^= x0; }
  x0 += ks2; x1 += k0 + 2u;
  for(int i=0;i<4;i++){ x0 += x1; x1 = rotl32(x1, ra[i]); x1 ^= x0; }
  x0 += k0; x1 += k1 + 3u;
  for(int i=0;i<4;i++){ x0 += x1; x1 = rotl32(x1, rb[i]); x1 ^= x0; }
  x0 += k1; x1 += ks2 + 4u;
  for(int i=0;i<4;i++){ x0 += x1; x1 = rotl32(x1, ra[i]); x1 ^= x0; }
  x0 += ks2; x1 += k0 + 5u;
  o0 = x0; o1 = x1;
}

static void jax_split_child(uint32_t ka, uint32_t kb, uint32_t i,
                            uint32_t& oa, uint32_t& ob){
  tf2x32(ka, kb, 0u, i, oa, ob);
}

static uint32_t jax_bits32(uint32_t ka, uint32_t kb, uint32_t i){
  uint32_t a,b; tf2x32(ka, kb, 0u, i, a, b);
  return a ^ b;
}

static void jax_perm64(uint32_t ka, uint32_t kb, int* perm){
  uint32_t sa, sb; jax_split_child(ka, kb, 1u, sa, sb);
  uint32_t b[64]; int v[64];
  for(int i=0;i<64;i++){ b[i]=jax_bits32(sa, sb, (uint32_t)i); v[i]=i; }
  for(int i=1;i<64;i++){
    uint32_t bb=b[i]; int vv=v[i]; int j=i-1;
    while(j>=0 && b[j]>bb){ b[j+1]=b[j]; v[j+1]=v[j]; j--; }
    b[j+1]=bb; v[j+1]=vv;
  }
  for(int i=0;i<64;i++) perm[i]=v[i];
}

static void compute_cols(ColsBoth& cb){
  uint32_t k1a,k1b,k2a,k2b;
  jax_split_child(0u, 42u, 0u, k1a, k1b);
  jax_split_child(0u, 42u, 1u, k2a, k2b);
  for(int side=0; side<2; side++){
    uint32_t ka = side ? k2a : k1a;
    uint32_t kb = side ? k2b : k1b;
    uint32_t nka,nkb, c1a,c1b, c2a,c2b;
    jax_split_child(ka,kb,0u,nka,nkb);
    jax_split_child(ka,kb,1u,c1a,c1b);
    jax_split_child(ka,kb,2u,c2a,c2b);
    int p[64];
    jax_perm64(c1a,c1b,p); for(int i=0;i<25;i++) cb.c[side].o25[i]=p[i];
    jax_perm64(c2a,c2b,p); for(int i=0;i<25;i++) cb.c[side].i25[i]=p[i];
    uint32_t d1a,d1b,d2a,d2b;
    jax_split_child(nka,nkb,1u,d1a,d1b);
    jax_split_child(nka,nkb,2u,d2a,d2b);
    jax_perm64(d1a,d1b,p); for(int i=0;i<10;i++) cb.c[side].o10[i]=p[i];
    jax_perm64(d2a,d2b,p); for(int i=0;i<10;i++) cb.c[side].i10[i]=p[i];
  }
}

// ---------------- device helpers ----------------
__device__ __forceinline__ float getc(const float4& v, int i){
  return (i==0)?v.x:(i==1)?v.y:(i==2)?v.z:v.w;
}
__device__ __forceinline__ float sigf(float x){ return 1.0f/(1.0f+expf(-x)); }
__device__ __forceinline__ void add4(float4& s, const float4& v){
  s.x+=v.x; s.y+=v.y; s.z+=v.z; s.w+=v.w;
}

// ---------------- kernels ----------------

// Gather + mean-aggregate with sampling fused inline. (verbatim round-4, measured 63 us)
__global__ __launch_bounds__(256) void gather_kernel(
    const float* __restrict__ feat,
    const int* __restrict__ nodes1, const int* __restrict__ nodes2,
    const int* __restrict__ nout, const int* __restrict__ nin,
    float* __restrict__ agg, int base_row, ColsBoth cb)
{
  int t = threadIdx.x;
  int row_local = blockIdx.x*8 + (t>>5);
  int lane = t & 31;
  int c0 = lane*4;
  int row = base_row + row_local;

  float4 selfv, so, si;

  if(row < 512){                       // hop0
    int side = row >> 8, b = row & 255;
    int node = (side ? nodes2 : nodes1)[b];
    const Cols& c = cb.c[side];
    const long nb = (long)node*64;
    selfv = *(const float4*)(feat + (long)node*FDIM + c0);
    int ido[25], idi[25];
    #pragma unroll
    for(int i=0;i<25;i++) ido[i] = nout[nb + c.o25[i]];
    #pragma unroll
    for(int i=0;i<25;i++) idi[i] = nin[nb + c.i25[i]];
    float4 acco = make_float4(0,0,0,0);
    float4 acci = make_float4(0,0,0,0);
    #pragma unroll
    for(int jj=0; jj<25; jj+=5){
      float4 vo[5], vi[5];
      #pragma unroll
      for(int i=0;i<5;i++) vo[i] = *(const float4*)(feat + (long)ido[jj+i]*FDIM + c0);
      #pragma unroll
      for(int i=0;i<5;i++) vi[i] = *(const float4*)(feat + (long)idi[jj+i]*FDIM + c0);
      #pragma unroll
      for(int i=0;i<5;i++) add4(acco, vo[i]);
      #pragma unroll
      for(int i=0;i<5;i++) add4(acci, vi[i]);
    }
    so = make_float4(acco.x/25.f, acco.y/25.f, acco.z/25.f, acco.w/25.f);
    si = make_float4(acci.x/25.f, acci.y/25.f, acci.z/25.f, acci.w/25.f);
  } else {                             // hop1
    int hrow = row - 512;
    int side = (hrow >= 12800) ? 1 : 0;
    int r = side ? (hrow - 12800) : hrow;
    int b = r / 50, slot = r % 50;
    const Cols& c = cb.c[side];
    int root = (side ? nodes2 : nodes1)[b];
    int node;
    if(slot < 25) node = nout[(long)root*64 + c.o25[slot]];
    else          node = nin [(long)root*64 + c.i25[slot-25]];
    const long nb = (long)node*64;
    selfv = *(const float4*)(feat + (long)node*FDIM + c0);
    int oid[10], iid[10];
    #pragma unroll
    for(int j=0;j<10;j++) oid[j] = nout[nb + c.o10[j]];
    #pragma unroll
    for(int j=0;j<10;j++) iid[j] = nin[nb + c.i10[j]];
    float4 acco = make_float4(0,0,0,0);
    float4 acci = make_float4(0,0,0,0);
    #pragma unroll
    for(int jj=0; jj<10; jj+=5){
      float4 vo[5], vi[5];
      #pragma unroll
      for(int j=0;j<5;j++) vo[j] = *(const float4*)(feat + (long)oid[jj+j]*FDIM + c0);
      #pragma unroll
      for(int j=0;j<5;j++) vi[j] = *(const float4*)(feat + (long)iid[jj+j]*FDIM + c0);
      #pragma unroll
      for(int j=0;j<5;j++) add4(acco, vo[j]);
      #pragma unroll
      for(int j=0;j<5;j++) add4(acci, vi[j]);
    }
    so = make_float4(acco.x*0.1f, acco.y*0.1f, acco.z*0.1f, acco.w*0.1f);
    si = make_float4(acci.x*0.1f, acci.y*0.1f, acci.z*0.1f, acci.w*0.1f);
  }

  float* ar = agg + (long)row_local*KDIM;
  *(float4*)(ar + c0)       = selfv;
  *(float4*)(ar + 128 + c0) = so;
  *(float4*)(ar + 256 + c0) = si;
}

// GEMM + sigmoid, L2-direct W (no LDS, no barriers).
// 1-wave blocks: 64 threads = 16 lanes(8 cols) x 4 rg(4 rows) -> 16 rows/block,
// 1632 blocks (6.4/CU, ~10% ceil-imbalance vs 25% at 408 blocks).
// Per k4 per thread: 4 A-loads (16B, L2) + 8 W-loads (wave-contiguous 512B
// broadcast, L2-resident 196KB) + 128 FMA. No LDS staging -> no vmcnt(0)
// chunk drains; occupancy VGPR-limited (~6 waves/SIMD) instead of LDS-limited.
__global__ __launch_bounds__(64) void gemm_sig_kernel(
    const float* __restrict__ A, const float* __restrict__ W,
    float* __restrict__ out)
{
  int t = threadIdx.x, lane = t&15, rg = t>>4;
  int r0 = blockIdx.x*16 + rg*4;
  int c0 = lane*8;
  float acc[4][8];
  #pragma unroll
  for(int r=0;r<4;r++)
    #pragma unroll
    for(int i=0;i<8;i++) acc[r][i]=0.f;

  const float* Ab = A + (long)r0*KDIM;
  const float* Wb = W + c0;
  #pragma unroll 2
  for(int k4=0;k4<KDIM;k4+=4){
    float4 a0 = *(const float4*)(Ab + 0*KDIM + k4);
    float4 a1 = *(const float4*)(Ab + 1*KDIM + k4);
    float4 a2 = *(const float4*)(Ab + 2*KDIM + k4);
    float4 a3 = *(const float4*)(Ab + 3*KDIM + k4);
    #pragma unroll
    for(int kk=0;kk<4;kk++){
      const float* wr = Wb + (long)(k4+kk)*FDIM;
      float4 w0 = *(const float4*)wr;
      float4 w1 = *(const float4*)(wr+4);
      float av0=getc(a0,kk), av1=getc(a1,kk), av2=getc(a2,kk), av3=getc(a3,kk);
      acc[0][0]+=av0*w0.x; acc[0][1]+=av0*w0.y; acc[0][2]+=av0*w0.z; acc[0][3]+=av0*w0.w;
      acc[0][4]+=av0*w1.x; acc[0][5]+=av0*w1.y; acc[0][6]+=av0*w1.z; acc[0][7]+=av0*w1.w;
      acc[1][0]+=av1*w0.x; acc[1][1]+=av1*w0.y; acc[1][2]+=av1*w0.z; acc[1][3]+=av1*w0.w;
      acc[1][4]+=av1*w1.x; acc[1][5]+=av1*w1.y; acc[1][6]+=av1*w1.z; acc[1][7]+=av1*w1.w;
      acc[2][0]+=av2*w0.x; acc[2][1]+=av2*w0.y; acc[2][2]+=av2*w0.z; acc[2][3]+=av2*w0.w;
      acc[2][4]+=av2*w1.x; acc[2][5]+=av2*w1.y; acc[2][6]+=av2*w1.z; acc[2][7]+=av2*w1.w;
      acc[3][0]+=av3*w0.x; acc[3][1]+=av3*w0.y; acc[3][2]+=av3*w0.z; acc[3][3]+=av3*w0.w;
      acc[3][4]+=av3*w1.x; acc[3][5]+=av3*w1.y; acc[3][6]+=av3*w1.z; acc[3][7]+=av3*w1.w;
    }
  }
  #pragma unroll
  for(int r=0;r<4;r++){
    float4 o0, o1;
    o0.x=sigf(acc[r][0]); o0.y=sigf(acc[r][1]); o0.z=sigf(acc[r][2]); o0.w=sigf(acc[r][3]);
    o1.x=sigf(acc[r][4]); o1.y=sigf(acc[r][5]); o1.z=sigf(acc[r][6]); o1.w=sigf(acc[r][7]);
    float* op = out + (long)(r0+r)*FDIM + c0;
    *(float4*)op = o0; *(float4*)(op+4) = o1;
  }
}

// Fused layer-1 agg + head GEMM + sigmoid + 128->64 projection.
// (verbatim round-6: grid 1536, 1 row/block, split-k + LDS tree-reduce)
__global__ __launch_bounds__(256) void head_kernel(
    const float* __restrict__ h,        // [26112][128]: rows 0..511 = h0, 512.. = h1
    const float* __restrict__ Wm, const float* __restrict__ Ws, const float* __restrict__ Wp,
    const float* __restrict__ Dm, const float* __restrict__ Ds, const float* __restrict__ Dp,
    float* __restrict__ out)            // [6][256][64]
{
  __shared__ float As[KDIM];            // 1.5 KB: [self|out-mean|in-mean]
  __shared__ float Ps[4*FDIM];          // 2 KB: phase-2 partials
  __shared__ float Hs[FDIM];            // 0.5 KB
  __shared__ float Qs[4*64];            // 1 KB: phase-3 partials
  int head = blockIdx.x >> 9;           // 0..2
  int grow = blockIdx.x & 511;          // 0..511
  int t = threadIdx.x;
  const float* W = (head==0) ? Wm : (head==1) ? Ws : Wp;
  const float* D = (head==0) ? Dm : (head==1) ? Ds : Dp;

  // phase 1: aggregation. c = t&127 channel; half 0 -> out(25)+self, half 1 -> in(25).
  {
    int c = t & 127;
    int half = t >> 7;
    const float* nb = h + (long)(512 + grow*50 + half*25)*FDIM + c;
    float s = 0.f;
    #pragma unroll
    for(int jj=0;jj<25;jj+=5){
      float v0 = nb[(long)(jj+0)*FDIM];
      float v1 = nb[(long)(jj+1)*FDIM];
      float v2 = nb[(long)(jj+2)*FDIM];
      float v3 = nb[(long)(jj+3)*FDIM];
      float v4 = nb[(long)(jj+4)*FDIM];
      s += v0+v1+v2+v3+v4;
    }
    As[128 + half*128 + c] = s/25.f;
    if(half==0) As[c] = h[(long)grow*FDIM + c];
  }
  __syncthreads();

  // phase 2: GEMM 384->128 + sigmoid. Thread = 2 cols (float2), k split 4x96.
  {
    int c2 = (t & 63)*2;
    int kq = t >> 6;                    // 0..3
    const float* wp = W + (long)(kq*96)*FDIM + c2;
    const float* as = As + kq*96;
    float a0=0.f, a1=0.f;
    #pragma unroll 8
    for(int k=0;k<96;k++){
      float a = as[k];
      float2 w = *(const float2*)(wp + (long)k*FDIM);
      a0 += a*w.x; a1 += a*w.y;
    }
    Ps[kq*FDIM + c2]   = a0;
    Ps[kq*FDIM + c2+1] = a1;
  }
  __syncthreads();
  if(t < 64){
    int c2 = t*2;
    float s0 = Ps[c2]     + Ps[FDIM+c2]     + Ps[2*FDIM+c2]     + Ps[3*FDIM+c2];
    float s1 = Ps[c2+1]   + Ps[FDIM+c2+1]   + Ps[2*FDIM+c2+1]   + Ps[3*FDIM+c2+1];
    Hs[c2]   = sigf(s0);
    Hs[c2+1] = sigf(s1);
  }
  __syncthreads();

  // phase 3: projection 128->64. Thread = 1 col, k split 4x32.
  {
    int col = t & 63;
    int kq = t >> 6;                    // 0..3
    const float* dp = D + (long)(kq*32)*64 + col;
    const float* hs = Hs + kq*32;
    float a = 0.f;
    #pragma unroll 8
    for(int k=0;k<32;k++){
      a += hs[k] * dp[(long)k*64];
    }
    Qs[kq*64 + col] = a;
  }
  __syncthreads();
  if(t < 64){
    float a = Qs[t] + Qs[64+t] + Qs[128+t] + Qs[192+t];
    int side = grow >> 8, b = grow & 255;
    out[((long)(side*3+head)*256 + b)*64 + t] = a;
  }
}

// ---------------- launch ----------------
extern "C" void kernel_launch(void* const* d_in, const int* in_sizes, int n_in,
                              void* d_out, int out_size, void* d_ws, size_t ws_size,
                              hipStream_t stream) {
  const int*   nodes1  = (const int*)d_in[0];
  const int*   nodes2  = (const int*)d_in[1];
  const int*   nout    = (const int*)d_in[2];
  const int*   nin     = (const int*)d_in[3];
  const float* feat    = (const float*)d_in[4];
  const float* W_in    = (const float*)d_in[5];
  const float* W_mean  = (const float*)d_in[6];
  const float* W_std   = (const float*)d_in[7];
  const float* W_pi    = (const float*)d_in[8];
  const float* Wd_mean = (const float*)d_in[11];
  const float* Wd_std  = (const float*)d_in[12];
  const float* Wd_pi   = (const float*)d_in[13];
  float* out = (float*)d_out;

  // workspace: h[26112][128] | aggChunk
  float* h    = (float*)d_ws;                          // 26112*128
  float* aggC = h + (size_t)NROWS*FDIM;

  // chunk count: smallest that fits ws (constant per session -> graph-safe).
  // chunkRows divisible by 16 (gemm) and 8 (gather); all ncOpt sizes qualify.
  size_t fixedB = (size_t)NROWS*FDIM*4;
  const int ncOpt[5] = {1,2,4,12,51};
  int nc = 51;
  for(int i=0;i<5;i++){
    size_t need = fixedB + ((size_t)NROWS/ncOpt[i])*KDIM*4;
    if(need <= ws_size){ nc = ncOpt[i]; break; }
  }
  int chunkRows = NROWS / nc;

  ColsBoth cb;
  compute_cols(cb);

  for(int c=0;c<nc;c++){
    int base = c*chunkRows;
    gather_kernel<<<chunkRows/8, 256, 0, stream>>>(feat, nodes1, nodes2,
                                                   nout, nin, aggC, base, cb);
    gemm_sig_kernel<<<chunkRows/16, 64, 0, stream>>>(aggC, W_in, h + (size_t)base*FDIM);
  }
  head_kernel<<<1536, 256, 0, stream>>>(h, W_mean, W_std, W_pi, Wd_mean, Wd_std, Wd_pi, out);
}

// Round 8
// 321.534 us; speedup vs baseline: 1.4003x; 1.4003x over previous
//
#include <hip/hip_runtime.h>
#include <stdint.h>
#include <math.h>

#define FDIM 128
#define KDIM 384
#define NROWS 26112   // 512 hop0 rows + 25600 hop1 rows
#define ASTRIDE 388   // 384+4 pad: gemm A-rows land on distinct bank groups
#define BROWS 32      // rows per fused block
#define KCH 48        // W k-chunk

struct Cols { int o25[25]; int i25[25]; int o10[10]; int i10[10]; };
struct ColsBoth { Cols c[2]; };

// ---------------- host-side JAX threefry (partitionable=True) ----------------
static inline uint32_t rotl32(uint32_t x, uint32_t r){ return (x<<r)|(x>>(32u-r)); }

static void tf2x32(uint32_t k0, uint32_t k1, uint32_t c0, uint32_t c1,
                   uint32_t& o0, uint32_t& o1){
  const uint32_t ra[4] = {13u,15u,26u,6u};
  const uint32_t rb[4] = {17u,29u,16u,24u};
  uint32_t ks2 = k0 ^ k1 ^ 0x1BD11BDAu;
  uint32_t x0 = c0 + k0, x1 = c1 + k1;
  for(int i=0;i<4;i++){ x0 += x1; x1 = rotl32(x1, ra[i]); x1 ^= x0; }
  x0 += k1; x1 += ks2 + 1u;
  for(int i=0;i<4;i++){ x0 += x1; x1 = rotl32(x1, rb[i]); x1 ^= x0; }
  x0 += ks2; x1 += k0 + 2u;
  for(int i=0;i<4;i++){ x0 += x1; x1 = rotl32(x1, ra[i]); x1 ^= x0; }
  x0 += k0; x1 += k1 + 3u;
  for(int i=0;i<4;i++){ x0 += x1; x1 = rotl32(x1, rb[i]); x1 ^= x0; }
  x0 += k1; x1 += ks2 + 4u;
  for(int i=0;i<4;i++){ x0 += x1; x1 = rotl32(x1, ra[i]); x1 ^= x0; }
  x0 += ks2; x1 += k0 + 5u;
  o0 = x0; o1 = x1;
}

static void jax_split_child(uint32_t ka, uint32_t kb, uint32_t i,
                            uint32_t& oa, uint32_t& ob){
  tf2x32(ka, kb, 0u, i, oa, ob);
}

static uint32_t jax_bits32(uint32_t ka, uint32_t kb, uint32_t i){
  uint32_t a,b; tf2x32(ka, kb, 0u, i, a, b);
  return a ^ b;
}

static void jax_perm64(uint32_t ka, uint32_t kb, int* perm){
  uint32_t sa, sb; jax_split_child(ka, kb, 1u, sa, sb);
  uint32_t b[64]; int v[64];
  for(int i=0;i<64;i++){ b[i]=jax_bits32(sa, sb, (uint32_t)i); v[i]=i; }
  for(int i=1;i<64;i++){
    uint32_t bb=b[i]; int vv=v[i]; int j=i-1;
    while(j>=0 && b[j]>bb){ b[j+1]=b[j]; v[j+1]=v[j]; j--; }
    b[j+1]=bb; v[j+1]=vv;
  }
  for(int i=0;i<64;i++) perm[i]=v[i];
}

static void compute_cols(ColsBoth& cb){
  uint32_t k1a,k1b,k2a,k2b;
  jax_split_child(0u, 42u, 0u, k1a, k1b);
  jax_split_child(0u, 42u, 1u, k2a, k2b);
  for(int side=0; side<2; side++){
    uint32_t ka = side ? k2a : k1a;
    uint32_t kb = side ? k2b : k1b;
    uint32_t nka,nkb, c1a,c1b, c2a,c2b;
    jax_split_child(ka,kb,0u,nka,nkb);
    jax_split_child(ka,kb,1u,c1a,c1b);
    jax_split_child(ka,kb,2u,c2a,c2b);
    int p[64];
    jax_perm64(c1a,c1b,p); for(int i=0;i<25;i++) cb.c[side].o25[i]=p[i];
    jax_perm64(c2a,c2b,p); for(int i=0;i<25;i++) cb.c[side].i25[i]=p[i];
    uint32_t d1a,d1b,d2a,d2b;
    jax_split_child(nka,nkb,1u,d1a,d1b);
    jax_split_child(nka,nkb,2u,d2a,d2b);
    jax_perm64(d1a,d1b,p); for(int i=0;i<10;i++) cb.c[side].o10[i]=p[i];
    jax_perm64(d2a,d2b,p); for(int i=0;i<10;i++) cb.c[side].i10[i]=p[i];
  }
}

// ---------------- device helpers ----------------
__device__ __forceinline__ float getc(const float4& v, int i){
  return (i==0)?v.x:(i==1)?v.y:(i==2)?v.z:v.w;
}
__device__ __forceinline__ float sigf(float x){ return 1.0f/(1.0f+expf(-x)); }
__device__ __forceinline__ void add4(float4& s, const float4& v){
  s.x+=v.x; s.y+=v.y; s.z+=v.z; s.w+=v.w;
}

// ---------------- kernels ----------------

// Fused gather + mean-aggregate + LDS-staged GEMM(384->128) + sigmoid.
// 32 rows/block, 816 blocks, 73 KB LDS -> 2 resident blocks/CU (phases of
// different blocks overlap; fixes R3's 1-block phase-lock and R7's
// no-LDS latency bind).
// Phase A (gather, proven R4 structure): 32-lane group does 4 sequential
// rows, agg row -> LDS As[32][388] (padded).
// Phase B (gemm, proven R0 structure): 8 chunks of 48 k; W chunk staged in
// LDS (24 KB); thread = 2 rows x 8 cols; A from LDS (16-lane broadcast).
__global__ __launch_bounds__(256) void fused_gg_kernel(
    const float* __restrict__ feat,
    const int* __restrict__ nodes1, const int* __restrict__ nodes2,
    const int* __restrict__ nout, const int* __restrict__ nin,
    const float* __restrict__ W,
    float* __restrict__ h, ColsBoth cb)
{
  __shared__ float As[BROWS*ASTRIDE];  // 48.5 KB
  __shared__ float Wbuf[KCH*FDIM];     // 24 KB
  int t = threadIdx.x;

  // ---------------- gather phase ----------------
  {
    int g = t >> 5;                    // 32-lane group 0..7
    int lane = t & 31;
    int c0 = lane*4;
    #pragma unroll 1
    for(int rr=0; rr<4; rr++){
      int lrow = rr*8 + g;
      int row = blockIdx.x*BROWS + lrow;
      float4 selfv, so, si;

      if(row < 512){                   // hop0
        int side = row >> 8, b = row & 255;
        int node = (side ? nodes2 : nodes1)[b];
        const Cols& c = cb.c[side];
        const long nb = (long)node*64;
        selfv = *(const float4*)(feat + (long)node*FDIM + c0);
        int ido[25], idi[25];
        #pragma unroll
        for(int i=0;i<25;i++) ido[i] = nout[nb + c.o25[i]];
        #pragma unroll
        for(int i=0;i<25;i++) idi[i] = nin[nb + c.i25[i]];
        float4 acco = make_float4(0,0,0,0);
        float4 acci = make_float4(0,0,0,0);
        #pragma unroll
        for(int jj=0; jj<25; jj+=5){
          float4 vo[5], vi[5];
          #pragma unroll
          for(int i=0;i<5;i++) vo[i] = *(const float4*)(feat + (long)ido[jj+i]*FDIM + c0);
          #pragma unroll
          for(int i=0;i<5;i++) vi[i] = *(const float4*)(feat + (long)idi[jj+i]*FDIM + c0);
          #pragma unroll
          for(int i=0;i<5;i++) add4(acco, vo[i]);
          #pragma unroll
          for(int i=0;i<5;i++) add4(acci, vi[i]);
        }
        so = make_float4(acco.x/25.f, acco.y/25.f, acco.z/25.f, acco.w/25.f);
        si = make_float4(acci.x/25.f, acci.y/25.f, acci.z/25.f, acci.w/25.f);
      } else {                         // hop1
        int hrow = row - 512;
        int side = (hrow >= 12800) ? 1 : 0;
        int r = side ? (hrow - 12800) : hrow;
        int b = r / 50, slot = r % 50;
        const Cols& c = cb.c[side];
        int root = (side ? nodes2 : nodes1)[b];
        int node;
        if(slot < 25) node = nout[(long)root*64 + c.o25[slot]];
        else          node = nin [(long)root*64 + c.i25[slot-25]];
        const long nb = (long)node*64;
        selfv = *(const float4*)(feat + (long)node*FDIM + c0);
        int oid[10], iid[10];
        #pragma unroll
        for(int j=0;j<10;j++) oid[j] = nout[nb + c.o10[j]];
        #pragma unroll
        for(int j=0;j<10;j++) iid[j] = nin[nb + c.i10[j]];
        float4 acco = make_float4(0,0,0,0);
        float4 acci = make_float4(0,0,0,0);
        #pragma unroll
        for(int jj=0; jj<10; jj+=5){
          float4 vo[5], vi[5];
          #pragma unroll
          for(int j=0;j<5;j++) vo[j] = *(const float4*)(feat + (long)oid[jj+j]*FDIM + c0);
          #pragma unroll
          for(int j=0;j<5;j++) vi[j] = *(const float4*)(feat + (long)iid[jj+j]*FDIM + c0);
          #pragma unroll
          for(int j=0;j<5;j++) add4(acco, vo[j]);
          #pragma unroll
          for(int j=0;j<5;j++) add4(acci, vi[j]);
        }
        so = make_float4(acco.x*0.1f, acco.y*0.1f, acco.z*0.1f, acco.w*0.1f);
        si = make_float4(acci.x*0.1f, acci.y*0.1f, acci.z*0.1f, acci.w*0.1f);
      }

      float* ar = As + lrow*ASTRIDE;
      *(float4*)(ar + c0)       = selfv;
      *(float4*)(ar + 128 + c0) = so;
      *(float4*)(ar + 256 + c0) = si;
    }
  }

  // ---------------- gemm phase ----------------
  {
    int lane = t & 15, rg = t >> 4;    // 16 rgs x 2 rows
    int c0 = lane*8;
    float acc[2][8];
    #pragma unroll
    for(int r=0;r<2;r++)
      #pragma unroll
      for(int i=0;i<8;i++) acc[r][i]=0.f;

    for(int kc=0; kc<8; kc++){
      __syncthreads();                 // 1st iter: also covers gather->As
      const float4* ws = (const float4*)(W + kc*KCH*FDIM);
      float4* wd = (float4*)Wbuf;
      #pragma unroll
      for(int i=0;i<6;i++) wd[i*256+t] = ws[i*256+t];
      __syncthreads();
      const float* Ab = As + (long)(rg*2)*ASTRIDE + kc*KCH;
      #pragma unroll 2
      for(int k4=0;k4<KCH;k4+=4){
        float4 a0 = *(const float4*)(Ab + k4);
        float4 a1 = *(const float4*)(Ab + ASTRIDE + k4);
        #pragma unroll
        for(int kk=0;kk<4;kk++){
          const float* wr = Wbuf + (k4+kk)*FDIM + c0;
          float4 w0 = *(const float4*)wr;
          float4 w1 = *(const float4*)(wr+4);
          float av0=getc(a0,kk), av1=getc(a1,kk);
          acc[0][0]+=av0*w0.x; acc[0][1]+=av0*w0.y; acc[0][2]+=av0*w0.z; acc[0][3]+=av0*w0.w;
          acc[0][4]+=av0*w1.x; acc[0][5]+=av0*w1.y; acc[0][6]+=av0*w1.z; acc[0][7]+=av0*w1.w;
          acc[1][0]+=av1*w0.x; acc[1][1]+=av1*w0.y; acc[1][2]+=av1*w0.z; acc[1][3]+=av1*w0.w;
          acc[1][4]+=av1*w1.x; acc[1][5]+=av1*w1.y; acc[1][6]+=av1*w1.z; acc[1][7]+=av1*w1.w;
        }
      }
    }
    #pragma unroll
    for(int r=0;r<2;r++){
      float4 o0, o1;
      o0.x=sigf(acc[r][0]); o0.y=sigf(acc[r][1]); o0.z=sigf(acc[r][2]); o0.w=sigf(acc[r][3]);
      o1.x=sigf(acc[r][4]); o1.y=sigf(acc[r][5]); o1.z=sigf(acc[r][6]); o1.w=sigf(acc[r][7]);
      long grow = (long)blockIdx.x*BROWS + rg*2 + r;
      float* op = h + grow*FDIM + c0;
      *(float4*)op = o0; *(float4*)(op+4) = o1;
    }
  }
}

// Fused layer-1 agg + head GEMM + sigmoid + 128->64 projection.
// (verbatim round-6: grid 1536, 1 row/block, split-k + LDS tree-reduce)
__global__ __launch_bounds__(256) void head_kernel(
    const float* __restrict__ h,        // [26112][128]: rows 0..511 = h0, 512.. = h1
    const float* __restrict__ Wm, const float* __restrict__ Ws, const float* __restrict__ Wp,
    const float* __restrict__ Dm, const float* __restrict__ Ds, const float* __restrict__ Dp,
    float* __restrict__ out)            // [6][256][64]
{
  __shared__ float As[KDIM];            // 1.5 KB: [self|out-mean|in-mean]
  __shared__ float Ps[4*FDIM];          // 2 KB: phase-2 partials
  __shared__ float Hs[FDIM];            // 0.5 KB
  __shared__ float Qs[4*64];            // 1 KB: phase-3 partials
  int head = blockIdx.x >> 9;           // 0..2
  int grow = blockIdx.x & 511;          // 0..511
  int t = threadIdx.x;
  const float* W = (head==0) ? Wm : (head==1) ? Ws : Wp;
  const float* D = (head==0) ? Dm : (head==1) ? Ds : Dp;

  // phase 1: aggregation. c = t&127 channel; half 0 -> out(25)+self, half 1 -> in(25).
  {
    int c = t & 127;
    int half = t >> 7;
    const float* nb = h + (long)(512 + grow*50 + half*25)*FDIM + c;
    float s = 0.f;
    #pragma unroll
    for(int jj=0;jj<25;jj+=5){
      float v0 = nb[(long)(jj+0)*FDIM];
      float v1 = nb[(long)(jj+1)*FDIM];
      float v2 = nb[(long)(jj+2)*FDIM];
      float v3 = nb[(long)(jj+3)*FDIM];
      float v4 = nb[(long)(jj+4)*FDIM];
      s += v0+v1+v2+v3+v4;
    }
    As[128 + half*128 + c] = s/25.f;
    if(half==0) As[c] = h[(long)grow*FDIM + c];
  }
  __syncthreads();

  // phase 2: GEMM 384->128 + sigmoid. Thread = 2 cols (float2), k split 4x96.
  {
    int c2 = (t & 63)*2;
    int kq = t >> 6;                    // 0..3
    const float* wp = W + (long)(kq*96)*FDIM + c2;
    const float* as = As + kq*96;
    float a0=0.f, a1=0.f;
    #pragma unroll 8
    for(int k=0;k<96;k++){
      float a = as[k];
      float2 w = *(const float2*)(wp + (long)k*FDIM);
      a0 += a*w.x; a1 += a*w.y;
    }
    Ps[kq*FDIM + c2]   = a0;
    Ps[kq*FDIM + c2+1] = a1;
  }
  __syncthreads();
  if(t < 64){
    int c2 = t*2;
    float s0 = Ps[c2]     + Ps[FDIM+c2]     + Ps[2*FDIM+c2]     + Ps[3*FDIM+c2];
    float s1 = Ps[c2+1]   + Ps[FDIM+c2+1]   + Ps[2*FDIM+c2+1]   + Ps[3*FDIM+c2+1];
    Hs[c2]   = sigf(s0);
    Hs[c2+1] = sigf(s1);
  }
  __syncthreads();

  // phase 3: projection 128->64. Thread = 1 col, k split 4x32.
  {
    int col = t & 63;
    int kq = t >> 6;                    // 0..3
    const float* dp = D + (long)(kq*32)*64 + col;
    const float* hs = Hs + kq*32;
    float a = 0.f;
    #pragma unroll 8
    for(int k=0;k<32;k++){
      a += hs[k] * dp[(long)k*64];
    }
    Qs[kq*64 + col] = a;
  }
  __syncthreads();
  if(t < 64){
    float a = Qs[t] + Qs[64+t] + Qs[128+t] + Qs[192+t];
    int side = grow >> 8, b = grow & 255;
    out[((long)(side*3+head)*256 + b)*64 + t] = a;
  }
}

// ---------------- launch ----------------
extern "C" void kernel_launch(void* const* d_in, const int* in_sizes, int n_in,
                              void* d_out, int out_size, void* d_ws, size_t ws_size,
                              hipStream_t stream) {
  const int*   nodes1  = (const int*)d_in[0];
  const int*   nodes2  = (const int*)d_in[1];
  const int*   nout    = (const int*)d_in[2];
  const int*   nin     = (const int*)d_in[3];
  const float* feat    = (const float*)d_in[4];
  const float* W_in    = (const float*)d_in[5];
  const float* W_mean  = (const float*)d_in[6];
  const float* W_std   = (const float*)d_in[7];
  const float* W_pi    = (const float*)d_in[8];
  const float* Wd_mean = (const float*)d_in[11];
  const float* Wd_std  = (const float*)d_in[12];
  const float* Wd_pi   = (const float*)d_in[13];
  float* out = (float*)d_out;

  // workspace: only h[26112][128] (agg lives in LDS inside the fused kernel)
  float* h = (float*)d_ws;

  ColsBoth cb;
  compute_cols(cb);

  fused_gg_kernel<<<NROWS/BROWS, 256, 0, stream>>>(feat, nodes1, nodes2,
                                                   nout, nin, W_in, h, cb);
  head_kernel<<<1536, 256, 0, stream>>>(h, W_mean, W_std, W_pi, Wd_mean, Wd_std, Wd_pi, out);
}

// Round 9
// 313.135 us; speedup vs baseline: 1.4378x; 1.0268x over previous
//
#include <hip/hip_runtime.h>
#include <stdint.h>
#include <math.h>

#define FDIM 128
#define KDIM 384
#define NROWS 26112   // 512 hop0 rows + 25600 hop1 rows

struct Cols { int o25[25]; int i25[25]; int o10[10]; int i10[10]; };
struct ColsBoth { Cols c[2]; };

// ---------------- host-side JAX threefry (partitionable=True) ----------------
static inline uint32_t rotl32(uint32_t x, uint32_t r){ return (x<<r)|(x>>(32u-r)); }

static void tf2x32(uint32_t k0, uint32_t k1, uint32_t c0, uint32_t c1,
                   uint32_t& o0, uint32_t& o1){
  const uint32_t ra[4] = {13u,15u,26u,6u};
  const uint32_t rb[4] = {17u,29u,16u,24u};
  uint32_t ks2 = k0 ^ k1 ^ 0x1BD11BDAu;
  uint32_t x0 = c0 + k0, x1 = c1 + k1;
  for(int i=0;i<4;i++){ x0 += x1; x1 = rotl32(x1, ra[i]); x1 ^= x0; }
  x0 += k1; x1 += ks2 + 1u;
  for(int i=0;i<4;i++){ x0 += x1; x1 = rotl32(x1, rb[i]); x1 ^= x0; }
  x0 += ks2; x1 += k0 + 2u;
  for(int i=0;i<4;i++){ x0 += x1; x1 = rotl32(x1, ra[i]); x1 ^= x0; }
  x0 += k0; x1 += k1 + 3u;
  for(int i=0;i<4;i++){ x0 += x1; x1 = rotl32(x1, rb[i]); x1 ^= x0; }
  x0 += k1; x1 += ks2 + 4u;
  for(int i=0;i<4;i++){ x0 += x1; x1 = rotl32(x1, ra[i]); x1 ^= x0; }
  x0 += ks2; x1 += k0 + 5u;
  o0 = x0; o1 = x1;
}

static void jax_split_child(uint32_t ka, uint32_t kb, uint32_t i,
                            uint32_t& oa, uint32_t& ob){
  tf2x32(ka, kb, 0u, i, oa, ob);
}

static uint32_t jax_bits32(uint32_t ka, uint32_t kb, uint32_t i){
  uint32_t a,b; tf2x32(ka, kb, 0u, i, a, b);
  return a ^ b;
}

static void jax_perm64(uint32_t ka, uint32_t kb, int* perm){
  uint32_t sa, sb; jax_split_child(ka, kb, 1u, sa, sb);
  uint32_t b[64]; int v[64];
  for(int i=0;i<64;i++){ b[i]=jax_bits32(sa, sb, (uint32_t)i); v[i]=i; }
  for(int i=1;i<64;i++){
    uint32_t bb=b[i]; int vv=v[i]; int j=i-1;
    while(j>=0 && b[j]>bb){ b[j+1]=b[j]; v[j+1]=v[j]; j--; }
    b[j+1]=bb; v[j+1]=vv;
  }
  for(int i=0;i<64;i++) perm[i]=v[i];
}

static void compute_cols(ColsBoth& cb){
  uint32_t k1a,k1b,k2a,k2b;
  jax_split_child(0u, 42u, 0u, k1a, k1b);
  jax_split_child(0u, 42u, 1u, k2a, k2b);
  for(int side=0; side<2; side++){
    uint32_t ka = side ? k2a : k1a;
    uint32_t kb = side ? k2b : k1b;
    uint32_t nka,nkb, c1a,c1b, c2a,c2b;
    jax_split_child(ka,kb,0u,nka,nkb);
    jax_split_child(ka,kb,1u,c1a,c1b);
    jax_split_child(ka,kb,2u,c2a,c2b);
    int p[64];
    jax_perm64(c1a,c1b,p); for(int i=0;i<25;i++) cb.c[side].o25[i]=p[i];
    jax_perm64(c2a,c2b,p); for(int i=0;i<25;i++) cb.c[side].i25[i]=p[i];
    uint32_t d1a,d1b,d2a,d2b;
    jax_split_child(nka,nkb,1u,d1a,d1b);
    jax_split_child(nka,nkb,2u,d2a,d2b);
    jax_perm64(d1a,d1b,p); for(int i=0;i<10;i++) cb.c[side].o10[i]=p[i];
    jax_perm64(d2a,d2b,p); for(int i=0;i<10;i++) cb.c[side].i10[i]=p[i];
  }
}

// ---------------- device helpers ----------------
__device__ __forceinline__ float getc(const float4& v, int i){
  return (i==0)?v.x:(i==1)?v.y:(i==2)?v.z:v.w;
}
__device__ __forceinline__ float sigf(float x){ return 1.0f/(1.0f+expf(-x)); }
__device__ __forceinline__ void add4(float4& s, const float4& v){
  s.x+=v.x; s.y+=v.y; s.z+=v.z; s.w+=v.w;
}

// ---------------- kernels ----------------

// Gather + mean-aggregate with sampling fused inline. (verbatim round-4, measured 63 us)
__global__ __launch_bounds__(256) void gather_kernel(
    const float* __restrict__ feat,
    const int* __restrict__ nodes1, const int* __restrict__ nodes2,
    const int* __restrict__ nout, const int* __restrict__ nin,
    float* __restrict__ agg, int base_row, ColsBoth cb)
{
  int t = threadIdx.x;
  int row_local = blockIdx.x*8 + (t>>5);
  int lane = t & 31;
  int c0 = lane*4;
  int row = base_row + row_local;

  float4 selfv, so, si;

  if(row < 512){                       // hop0
    int side = row >> 8, b = row & 255;
    int node = (side ? nodes2 : nodes1)[b];
    const Cols& c = cb.c[side];
    const long nb = (long)node*64;
    selfv = *(const float4*)(feat + (long)node*FDIM + c0);
    int ido[25], idi[25];
    #pragma unroll
    for(int i=0;i<25;i++) ido[i] = nout[nb + c.o25[i]];
    #pragma unroll
    for(int i=0;i<25;i++) idi[i] = nin[nb + c.i25[i]];
    float4 acco = make_float4(0,0,0,0);
    float4 acci = make_float4(0,0,0,0);
    #pragma unroll
    for(int jj=0; jj<25; jj+=5){
      float4 vo[5], vi[5];
      #pragma unroll
      for(int i=0;i<5;i++) vo[i] = *(const float4*)(feat + (long)ido[jj+i]*FDIM + c0);
      #pragma unroll
      for(int i=0;i<5;i++) vi[i] = *(const float4*)(feat + (long)idi[jj+i]*FDIM + c0);
      #pragma unroll
      for(int i=0;i<5;i++) add4(acco, vo[i]);
      #pragma unroll
      for(int i=0;i<5;i++) add4(acci, vi[i]);
    }
    so = make_float4(acco.x/25.f, acco.y/25.f, acco.z/25.f, acco.w/25.f);
    si = make_float4(acci.x/25.f, acci.y/25.f, acci.z/25.f, acci.w/25.f);
  } else {                             // hop1
    int hrow = row - 512;
    int side = (hrow >= 12800) ? 1 : 0;
    int r = side ? (hrow - 12800) : hrow;
    int b = r / 50, slot = r % 50;
    const Cols& c = cb.c[side];
    int root = (side ? nodes2 : nodes1)[b];
    int node;
    if(slot < 25) node = nout[(long)root*64 + c.o25[slot]];
    else          node = nin [(long)root*64 + c.i25[slot-25]];
    const long nb = (long)node*64;
    selfv = *(const float4*)(feat + (long)node*FDIM + c0);
    int oid[10], iid[10];
    #pragma unroll
    for(int j=0;j<10;j++) oid[j] = nout[nb + c.o10[j]];
    #pragma unroll
    for(int j=0;j<10;j++) iid[j] = nin[nb + c.i10[j]];
    float4 acco = make_float4(0,0,0,0);
    float4 acci = make_float4(0,0,0,0);
    #pragma unroll
    for(int jj=0; jj<10; jj+=5){
      float4 vo[5], vi[5];
      #pragma unroll
      for(int j=0;j<5;j++) vo[j] = *(const float4*)(feat + (long)oid[jj+j]*FDIM + c0);
      #pragma unroll
      for(int j=0;j<5;j++) vi[j] = *(const float4*)(feat + (long)iid[jj+j]*FDIM + c0);
      #pragma unroll
      for(int j=0;j<5;j++) add4(acco, vo[j]);
      #pragma unroll
      for(int j=0;j<5;j++) add4(acci, vi[j]);
    }
    so = make_float4(acco.x*0.1f, acco.y*0.1f, acco.z*0.1f, acco.w*0.1f);
    si = make_float4(acci.x*0.1f, acci.y*0.1f, acci.z*0.1f, acci.w*0.1f);
  }

  float* ar = agg + (long)row_local*KDIM;
  *(float4*)(ar + c0)       = selfv;
  *(float4*)(ar + 128 + c0) = so;
  *(float4*)(ar + 256 + c0) = si;
}

// Blocked GEMM + sigmoid: 64 rows/block (408 blocks), thread = 4 rows x 8 cols.
// W staged in LDS in 4 chunks of 96 k. R0 structure (measured 53 us) with ONE
// change: column ownership c0 = lane*4 with two col-blocks {c0, 64+c0}
// (was lane*8). W-read per instruction now covers 64 contiguous dwords ->
// 2-way bank access (free, m136) instead of 4-way conflict (R8's fused
// kernel measured 1.0e7 SQ_LDS_BANK_CONFLICT cycles from the lane*8 pattern).
__global__ __launch_bounds__(256) void gemm_sig_kernel(
    const float* __restrict__ A, const float* __restrict__ W,
    float* __restrict__ out)
{
  __shared__ float Wbuf[96*128];       // 48 KB
  int t = threadIdx.x, lane = t&15, rg = t>>4;
  int r0 = blockIdx.x*64 + rg*4;
  int c0 = lane*4;                     // col block 1: [c0, c0+4); block 2: [64+c0, 64+c0+4)
  float acc[4][8];
  #pragma unroll
  for(int r=0;r<4;r++)
    #pragma unroll
    for(int i=0;i<8;i++) acc[r][i]=0.f;

  for(int kc=0; kc<4; kc++){
    __syncthreads();
    const float4* ws = (const float4*)(W + kc*96*128);
    float4* wd = (float4*)Wbuf;
    #pragma unroll
    for(int i=0;i<12;i++) wd[i*256+t] = ws[i*256+t];
    __syncthreads();
    const float* Ab = A + (long)r0*KDIM + kc*96;
    #pragma unroll 2
    for(int k4=0;k4<96;k4+=4){
      float4 a0 = *(const float4*)(Ab + 0*KDIM + k4);
      float4 a1 = *(const float4*)(Ab + 1*KDIM + k4);
      float4 a2 = *(const float4*)(Ab + 2*KDIM + k4);
      float4 a3 = *(const float4*)(Ab + 3*KDIM + k4);
      #pragma unroll
      for(int kk=0;kk<4;kk++){
        float av0=getc(a0,kk), av1=getc(a1,kk), av2=getc(a2,kk), av3=getc(a3,kk);
        const float* wr = Wbuf + (k4+kk)*128 + c0;
        float4 w0 = *(const float4*)wr;        // 16 lanes -> 64 contiguous dwords
        float4 w1 = *(const float4*)(wr+64);   // second col-block, same pattern
        acc[0][0]+=av0*w0.x; acc[0][1]+=av0*w0.y; acc[0][2]+=av0*w0.z; acc[0][3]+=av0*w0.w;
        acc[0][4]+=av0*w1.x; acc[0][5]+=av0*w1.y; acc[0][6]+=av0*w1.z; acc[0][7]+=av0*w1.w;
        acc[1][0]+=av1*w0.x; acc[1][1]+=av1*w0.y; acc[1][2]+=av1*w0.z; acc[1][3]+=av1*w0.w;
        acc[1][4]+=av1*w1.x; acc[1][5]+=av1*w1.y; acc[1][6]+=av1*w1.z; acc[1][7]+=av1*w1.w;
        acc[2][0]+=av2*w0.x; acc[2][1]+=av2*w0.y; acc[2][2]+=av2*w0.z; acc[2][3]+=av2*w0.w;
        acc[2][4]+=av2*w1.x; acc[2][5]+=av2*w1.y; acc[2][6]+=av2*w1.z; acc[2][7]+=av2*w1.w;
        acc[3][0]+=av3*w0.x; acc[3][1]+=av3*w0.y; acc[3][2]+=av3*w0.z; acc[3][3]+=av3*w0.w;
        acc[3][4]+=av3*w1.x; acc[3][5]+=av3*w1.y; acc[3][6]+=av3*w1.z; acc[3][7]+=av3*w1.w;
      }
    }
  }
  #pragma unroll
  for(int r=0;r<4;r++){
    float4 o0, o1;
    o0.x=sigf(acc[r][0]); o0.y=sigf(acc[r][1]); o0.z=sigf(acc[r][2]); o0.w=sigf(acc[r][3]);
    o1.x=sigf(acc[r][4]); o1.y=sigf(acc[r][5]); o1.z=sigf(acc[r][6]); o1.w=sigf(acc[r][7]);
    float* op = out + (long)(r0+r)*FDIM;
    *(float4*)(op + c0)      = o0;     // cols [c0, c0+4)
    *(float4*)(op + 64 + c0) = o1;     // cols [64+c0, 64+c0+4)
  }
}

// Fused layer-1 agg + head GEMM + sigmoid + 128->64 projection.
// (verbatim round-6: grid 1536, 1 row/block, split-k + LDS tree-reduce)
__global__ __launch_bounds__(256) void head_kernel(
    const float* __restrict__ h,        // [26112][128]: rows 0..511 = h0, 512.. = h1
    const float* __restrict__ Wm, const float* __restrict__ Ws, const float* __restrict__ Wp,
    const float* __restrict__ Dm, const float* __restrict__ Ds, const float* __restrict__ Dp,
    float* __restrict__ out)            // [6][256][64]
{
  __shared__ float As[KDIM];            // 1.5 KB: [self|out-mean|in-mean]
  __shared__ float Ps[4*FDIM];          // 2 KB: phase-2 partials
  __shared__ float Hs[FDIM];            // 0.5 KB
  __shared__ float Qs[4*64];            // 1 KB: phase-3 partials
  int head = blockIdx.x >> 9;           // 0..2
  int grow = blockIdx.x & 511;          // 0..511
  int t = threadIdx.x;
  const float* W = (head==0) ? Wm : (head==1) ? Ws : Wp;
  const float* D = (head==0) ? Dm : (head==1) ? Ds : Dp;

  // phase 1: aggregation. c = t&127 channel; half 0 -> out(25)+self, half 1 -> in(25).
  {
    int c = t & 127;
    int half = t >> 7;
    const float* nb = h + (long)(512 + grow*50 + half*25)*FDIM + c;
    float s = 0.f;
    #pragma unroll
    for(int jj=0;jj<25;jj+=5){
      float v0 = nb[(long)(jj+0)*FDIM];
      float v1 = nb[(long)(jj+1)*FDIM];
      float v2 = nb[(long)(jj+2)*FDIM];
      float v3 = nb[(long)(jj+3)*FDIM];
      float v4 = nb[(long)(jj+4)*FDIM];
      s += v0+v1+v2+v3+v4;
    }
    As[128 + half*128 + c] = s/25.f;
    if(half==0) As[c] = h[(long)grow*FDIM + c];
  }
  __syncthreads();

  // phase 2: GEMM 384->128 + sigmoid. Thread = 2 cols (float2), k split 4x96.
  {
    int c2 = (t & 63)*2;
    int kq = t >> 6;                    // 0..3
    const float* wp = W + (long)(kq*96)*FDIM + c2;
    const float* as = As + kq*96;
    float a0=0.f, a1=0.f;
    #pragma unroll 8
    for(int k=0;k<96;k++){
      float a = as[k];
      float2 w = *(const float2*)(wp + (long)k*FDIM);
      a0 += a*w.x; a1 += a*w.y;
    }
    Ps[kq*FDIM + c2]   = a0;
    Ps[kq*FDIM + c2+1] = a1;
  }
  __syncthreads();
  if(t < 64){
    int c2 = t*2;
    float s0 = Ps[c2]     + Ps[FDIM+c2]     + Ps[2*FDIM+c2]     + Ps[3*FDIM+c2];
    float s1 = Ps[c2+1]   + Ps[FDIM+c2+1]   + Ps[2*FDIM+c2+1]   + Ps[3*FDIM+c2+1];
    Hs[c2]   = sigf(s0);
    Hs[c2+1] = sigf(s1);
  }
  __syncthreads();

  // phase 3: projection 128->64. Thread = 1 col, k split 4x32.
  {
    int col = t & 63;
    int kq = t >> 6;                    // 0..3
    const float* dp = D + (long)(kq*32)*64 + col;
    const float* hs = Hs + kq*32;
    float a = 0.f;
    #pragma unroll 8
    for(int k=0;k<32;k++){
      a += hs[k] * dp[(long)k*64];
    }
    Qs[kq*64 + col] = a;
  }
  __syncthreads();
  if(t < 64){
    float a = Qs[t] + Qs[64+t] + Qs[128+t] + Qs[192+t];
    int side = grow >> 8, b = grow & 255;
    out[((long)(side*3+head)*256 + b)*64 + t] = a;
  }
}

// ---------------- launch ----------------
extern "C" void kernel_launch(void* const* d_in, const int* in_sizes, int n_in,
                              void* d_out, int out_size, void* d_ws, size_t ws_size,
                              hipStream_t stream) {
  const int*   nodes1  = (const int*)d_in[0];
  const int*   nodes2  = (const int*)d_in[1];
  const int*   nout    = (const int*)d_in[2];
  const int*   nin     = (const int*)d_in[3];
  const float* feat    = (const float*)d_in[4];
  const float* W_in    = (const float*)d_in[5];
  const float* W_mean  = (const float*)d_in[6];
  const float* W_std   = (const float*)d_in[7];
  const float* W_pi    = (const float*)d_in[8];
  const float* Wd_mean = (const float*)d_in[11];
  const float* Wd_std  = (const float*)d_in[12];
  const float* Wd_pi   = (const float*)d_in[13];
  float* out = (float*)d_out;

  // workspace: h[26112][128] | aggChunk
  float* h    = (float*)d_ws;                          // 26112*128
  float* aggC = h + (size_t)NROWS*FDIM;

  // chunk count: smallest that fits ws (constant per session -> graph-safe).
  // chunkRows divisible by 64 (gemm) and 8 (gather).
  size_t fixedB = (size_t)NROWS*FDIM*4;
  const int ncOpt[5] = {1,2,4,12,51};
  int nc = 51;
  for(int i=0;i<5;i++){
    size_t need = fixedB + ((size_t)NROWS/ncOpt[i])*KDIM*4;
    if(need <= ws_size){ nc = ncOpt[i]; break; }
  }
  int chunkRows = NROWS / nc;

  ColsBoth cb;
  compute_cols(cb);

  for(int c=0;c<nc;c++){
    int base = c*chunkRows;
    gather_kernel<<<chunkRows/8, 256, 0, stream>>>(feat, nodes1, nodes2,
                                                   nout, nin, aggC, base, cb);
    gemm_sig_kernel<<<chunkRows/64, 256, 0, stream>>>(aggC, W_in, h + (size_t)base*FDIM);
  }
  head_kernel<<<1536, 256, 0, stream>>>(h, W_mean, W_std, W_pi, Wd_mean, Wd_std, Wd_pi, out);
}